// Round 1
// 182.464 us; speedup vs baseline: 1.0137x; 1.0137x over previous
//
#include <hip/hip_runtime.h>
#include <hip/hip_bf16.h>
#include <stdint.h>

// QuantizedConv2d int8: x (32,128,56,56), w (256,128,3,3), pad 1, stride 1.
// Implicit GEMM on v_mfma_i32_32x32x32_i8. M=out-ch, N=pixels, K=9*128=1152.
// R10: 128-out-ch block tile (mt=4) -> 0.75 LDS b128 reads per MFMA (was 1.0,
// with 8x A redundancy). Weights streamed per-tap (16KB), double-buffered,
// prefetched under the previous tap's 32 MFMAs. LDS = 78,336 B -> 2 blocks/CU
// co-resident (stage/epilogue of one block hides under the other's MFMAs).
// Grid (14 rg, 32 n, 2 ktb): ktb slowest so round 2 re-reads xp from L3 not HBM.

#define NB   32
#define CIN  128
#define HO   56
#define WO   56
#define KOUT 256
#define HP   58
#define ROWB (HP * CIN)          // 7424 bytes per padded row

typedef int v4i  __attribute__((ext_vector_type(4)));
typedef int v16i __attribute__((ext_vector_type(16)));

static __device__ __forceinline__ void gload_lds16(const int8_t* g, int8_t* l) {
  __builtin_amdgcn_global_load_lds(
      (const __attribute__((address_space(1))) void*)g,
      (__attribute__((address_space(3))) void*)l, 16, 0, 0);
}

// ---------------- pack x: NCHW int32 -> padded NHWC int8 (int4 reads) --------
__global__ __launch_bounds__(256) void pack_x_kernel(const int* __restrict__ x,
                                                     int8_t* __restrict__ xp) {
  __shared__ int t32[128][57];       // 29,184 B, stride 57 to break conflicts
  const int tid = threadIdx.x;
  const int r = blockIdx.x;          // padded row 0..57
  const int n = blockIdx.y;
  const bool interior = (r >= 1) && (r <= HO);

  if (interior) {
    const int h = r - 1;
    const int* xrow = x + ((size_t)(n * CIN) * HO + h) * WO;  // c stride = 3136 ints
    #pragma unroll
    for (int it = 0; it < 7; ++it) {
      const int j = it * 256 + tid;  // < 1792 = 128 c x 14 w-quads
      const int c = j / 14;
      const int w4 = j - c * 14;
      const int4 v = *reinterpret_cast<const int4*>(xrow + c * 3136 + w4 * 4);
      t32[c][w4 * 4 + 0] = v.x;
      t32[c][w4 * 4 + 1] = v.y;
      t32[c][w4 * 4 + 2] = v.z;
      t32[c][w4 * 4 + 3] = v.w;
    }
  }
  __syncthreads();
  #pragma unroll
  for (int it = 0; it < 8; ++it) {
    const int i = it * 256 + tid;
    if (i < HP * 32) {
      const int w = i >> 5;          // padded col 0..57
      const int c4 = i & 31;
      int vv = 0;
      if (interior && w >= 1 && w <= WO) {
        const int b0 = t32[c4 * 4 + 0][w - 1] & 0xff;
        const int b1 = t32[c4 * 4 + 1][w - 1] & 0xff;
        const int b2 = t32[c4 * 4 + 2][w - 1] & 0xff;
        const int b3 = t32[c4 * 4 + 3][w - 1];
        vv = b0 | (b1 << 8) | (b2 << 16) | (b3 << 24);
      }
      *reinterpret_cast<int*>(xp + ((size_t)(n * HP + r) * HP + w) * CIN + c4 * 4) = vv;
    }
  }
}

// ---- pack w: OIHW int32 -> [ktb(2)][tap(9)][cc(8)][ch(128)] 16B chunks ------
__global__ __launch_bounds__(256) void pack_w_kernel(const int* __restrict__ wgt,
                                                     int8_t* __restrict__ wq) {
  const int wid = blockIdx.x * 256 + threadIdx.x;   // 0..73727 int32 words
  const int wi = wid & 3;
  const int ci = wid >> 2;                          // chunk 0..18431
  const int ktb = ci / 9216;                        // 9216 = 9*8*128
  const int r  = ci - ktb * 9216;
  const int tap = r >> 10;                          // 1024 = 8*128
  const int r2  = r & 1023;
  const int cc  = r2 >> 7;
  const int ch  = r2 & 127;
  const int k_global = ktb * 128 + ch;
  const int cin0 = cc * 16 + wi * 4;
  const int base = (k_global * CIN + cin0) * 9 + tap;  // OIHW, 3x3=9 taps
  const int v0 = wgt[base];
  const int v1 = wgt[base + 9];
  const int v2 = wgt[base + 18];
  const int v3 = wgt[base + 27];
  reinterpret_cast<int*>(wq)[wid] =
      (v0 & 0xff) | ((v1 & 0xff) << 8) | ((v2 & 0xff) << 16) | (v3 << 24);
}

// ---------------- conv: 128-ch tile, per-tap weight double-buffer ------------
// grid (14 rowgroups, 32 n, 2 ktb) = 896 blocks, 256 threads = 4 waves.
// Block: 128 out-ch x 4 output rows. Wave wr: row h0+wr, 128 ch x 64 px.
// acc[mt=4][nt=2] = 128 regs. Per ks: 4 A + 2 B b128 reads -> 8 MFMAs (0.75:1).
// LDS 78,336 B -> 2 blocks/CU. One barrier per tap; tap t+1 weights prefetch
// (4 global_load_lds per thread) issued before tap t's MFMAs.
__global__ __launch_bounds__(256, 2) void conv_kernel(const int8_t* __restrict__ xp,
                                                      const int8_t* __restrict__ wq,
                                                      const int* __restrict__ bias,
                                                      const float* __restrict__ wscale,
                                                      int* __restrict__ out) {
  __shared__ __align__(16) int8_t lw[2][8 * 128 * 16];   // 2 x 16,384 B: one tap each
  __shared__ __align__(16) int8_t lx[6 * HP * 8 * 16];   // 44,544 B: 6 padded rows
  __shared__ int   bsh[128];
  __shared__ float ssh[128];

  const int tid = threadIdx.x;
  const int rg = blockIdx.x;           // row group 0..13
  const int n_img = blockIdx.y;
  const int ktb = blockIdx.z;          // 128-ch slice (slowest: L3 reuse of xp)
  const int h0 = rg * 4;

  const int lane = tid & 63;
  const int wr = tid >> 6;             // wave = output row 0..3
  const int p0 = lane & 31;
  const int half = lane >> 5;

  const int8_t* xg = xp + ((size_t)(n_img * HP) + h0) * ROWB;
  const int8_t* wqt = wq + (size_t)ktb * (9 * 16384);

  // ---- stage pixels: 6 padded rows = 2784 chunks, XOR swizzle in source ----
  #pragma unroll
  for (int it = 0; it < 11; ++it) {
    const int i = it * 256 + tid;
    if (i < 6 * HP * 8) {
      const int pf = i >> 3;
      const int cc = (i & 7) ^ (pf & 7);
      gload_lds16(xg + pf * CIN + (cc << 4), lx + i * 16);
    }
  }
  // ---- stage weights tap 0: 1024 chunks, linear ----
  #pragma unroll
  for (int it = 0; it < 4; ++it) {
    const int j = it * 256 + tid;
    gload_lds16(wqt + j * 16, lw[0] + j * 16);
  }
  if (tid < 128) {
    const int ch = ktb * 128 + tid;
    bsh[tid] = bias[ch];
    ssh[tid] = (0.02f * wscale[ch]) / 0.05f;   // IN_SCALE * ws / OUT_SCALE
  }
  __syncthreads();

  v16i acc[4][2];                      // [mt: 32-ch tile][nt: 32-px tile]
  #pragma unroll
  for (int mt = 0; mt < 4; ++mt)
    #pragma unroll
    for (int nt = 0; nt < 2; ++nt)
      #pragma unroll
      for (int e = 0; e < 16; ++e) acc[mt][nt][e] = 0;

  #pragma unroll
  for (int tap = 0; tap < 9; ++tap) {
    // prefetch next tap's weights into the other buffer (drained at barrier)
    if (tap < 8) {
      const int8_t* wsrc = wqt + (tap + 1) * 16384;
      int8_t* ldst = lw[(tap + 1) & 1];
      #pragma unroll
      for (int it = 0; it < 4; ++it) {
        const int j = it * 256 + tid;
        gload_lds16(wsrc + j * 16, ldst + j * 16);
      }
    }
    const int kh = tap / 3, kw = tap - kh * 3;
    const int8_t* lwt = lw[tap & 1];             // [cc(8)][ch(128)] chunk-major
    const int pfb = (wr + kh) * HP + kw;
    #pragma unroll
    for (int ks = 0; ks < 4; ++ks) {
      const int cch = 2 * ks + half;             // k-chunk for this lane
      v4i a[4];
      #pragma unroll
      for (int mt = 0; mt < 4; ++mt)
        a[mt] = *reinterpret_cast<const v4i*>(lwt + cch * 2048 + (mt * 32 + p0) * 16);
      #pragma unroll
      for (int nt = 0; nt < 2; ++nt) {
        const int pf = pfb + nt * 32 + p0;
        const v4i b = *reinterpret_cast<const v4i*>(
            lx + pf * CIN + ((cch ^ (pf & 7)) << 4));
        #pragma unroll
        for (int mt = 0; mt < 4; ++mt)
          acc[mt][nt] = __builtin_amdgcn_mfma_i32_32x32x32_i8(a[mt], b, acc[mt][nt], 0, 0, 0);
      }
    }
    __syncthreads();                   // drains prefetch vmcnt; guards dbuf swap
  }

  // ---- epilogue: D row = ch = mt*32 + (r&3)+8*(r>>2)+4*half, col = pixel ----
  const int h = h0 + wr;
  #pragma unroll
  for (int mt = 0; mt < 4; ++mt) {
    #pragma unroll
    for (int r = 0; r < 16; ++r) {
      const int cl = mt * 32 + (r & 3) + 8 * (r >> 2) + 4 * half;
      const int bi = bsh[cl];
      const float sc = ssh[cl];
      int* ob = out + (((size_t)(n_img * KOUT + ktb * 128 + cl)) * HO + h) * WO;
      #pragma unroll
      for (int nt = 0; nt < 2; ++nt) {
        const int w = nt * 32 + p0;
        if (w < WO) {
          float v = (float)(acc[mt][nt][r] + bi) * sc;
          v = rintf(v);                          // round-half-even == jnp.round
          v = fminf(fmaxf(v, -128.0f), 127.0f);
          ob[w] = (int)v;
        }
      }
    }
  }
}

extern "C" void kernel_launch(void* const* d_in, const int* in_sizes, int n_in,
                              void* d_out, int out_size, void* d_ws, size_t ws_size,
                              hipStream_t stream) {
  const int* x = (const int*)d_in[0];
  const int* wgt = (const int*)d_in[1];
  const int* bias = (const int*)d_in[2];
  const float* wscale = (const float*)d_in[3];
  int* out = (int*)d_out;

  int8_t* xp = (int8_t*)d_ws;                               // 13,780,992 B
  int8_t* wq = (int8_t*)d_ws + (size_t)NB * HP * ROWB;      // 294,912 B

  pack_x_kernel<<<dim3(HP, NB), 256, 0, stream>>>(x, xp);
  pack_w_kernel<<<288, 256, 0, stream>>>(wgt, wq);
  conv_kernel<<<dim3(14, 32, 2), 256, 0, stream>>>(xp, wq, bias, wscale, out);
}